// Round 13
// baseline (1549.249 us; speedup 1.0000x reference)
//
#include <hip/hip_runtime.h>
#include <hip/hip_bf16.h>

#define N_   128
#define L_   512
#define NB_  4
#define D_   1024
#define H_   16
#define DH_  64
#define IN_  1024
#define T_   512

#define KS_  8       // GEMM K-splits (Kc = 128)
#define NCV_ 32      // attention chunks per sample (16 rows each)

typedef __attribute__((ext_vector_type(8))) short short8v;
typedef __attribute__((ext_vector_type(4))) float float4v;

__device__ __forceinline__ short f2bf(float f) {             // RNE f32->bf16
  unsigned u = __float_as_uint(f);
  u += 0x7FFFu + ((u >> 16) & 1u);
  return (short)(u >> 16);
}
__device__ __forceinline__ int pack2(float a, float b) {
  return (int)(unsigned short)f2bf(a) | ((int)f2bf(b) << 16);
}

// ---------------------------------------------------------------- pos table
__global__ __launch_bounds__(512) void pos_kernel(float* __restrict__ pos) {
  int t = blockIdx.x;
  int j = threadIdx.x;
  float seq = (float)(T_ - 1 - t);
  float ex  = (float)(2 * j) * (1.0f / (float)D_);
  float inv = expf(-ex * 9.210340371976184f);
  float si  = seq * inv;
  pos[(size_t)t * D_ + j]        = sinf(si);
  pos[(size_t)t * D_ + 512 + j]  = cosf(si);
}

// ---------------------------------------------------------------- A-operand fetch with fused combine
// AMODE 0: raw A[row][k]
// AMODE 1: sum_s gp1024[s][row][k] + aux[k]            (ao = Wo-out + bias)
// AMODE 2: relu(sum_s gp1024[s][row][k] + aux[k])      (fwd)
// AMODE 3: sigmoid(sum_s gp2048[s][row][k]) * aux[row*D+k]   (rq = r * x)
template<int AMODE>
__device__ __forceinline__ float4 a_fetch(const float* __restrict__ A,
                                          const float* __restrict__ gp,
                                          const float* __restrict__ aux,
                                          int row, int k) {
  if (AMODE == 0) {
    return *(const float4*)&A[(size_t)row * D_ + k];
  }
  constexpr int W = (AMODE == 3) ? 2048 : 1024;
  float4 a = {0.f, 0.f, 0.f, 0.f};
  #pragma unroll
  for (int s = 0; s < KS_; ++s) {
    float4 p = *(const float4*)&gp[(size_t)s * (N_ * W) + (size_t)row * W + k];
    a.x += p.x; a.y += p.y; a.z += p.z; a.w += p.w;
  }
  if (AMODE == 1) {
    float4 b = *(const float4*)&aux[k];
    a.x += b.x; a.y += b.y; a.z += b.z; a.w += b.w;
  } else if (AMODE == 2) {
    float4 b = *(const float4*)&aux[k];
    a.x = fmaxf(a.x + b.x, 0.f); a.y = fmaxf(a.y + b.y, 0.f);
    a.z = fmaxf(a.z + b.z, 0.f); a.w = fmaxf(a.w + b.w, 0.f);
  } else if (AMODE == 3) {
    float4 xm = *(const float4*)&aux[(size_t)row * D_ + k];
    a.x = (1.f / (1.f + __expf(-a.x))) * xm.x;
    a.y = (1.f / (1.f + __expf(-a.y))) * xm.y;
    a.z = (1.f / (1.f + __expf(-a.z))) * xm.z;
    a.w = (1.f / (1.f + __expf(-a.w))) * xm.w;
  }
  return a;
}

// ---------------------------------------------------------------- MFMA split-K GEMM partials (round-9 body)
// 256 threads = 4 waves; Kc=128; grid (32 col-tiles, 8 k-splits) = 256 blocks.
// A1M/A2M select the fused-combine staging mode; A2M=-1 -> single input product.
#define LDK_ 136   // padded k-row (shorts)
template<int COLW, int NC, int A1M, int A2M>
__global__ __launch_bounds__(256) void gemm_part_t(
    const float* __restrict__ A1, const float* __restrict__ gp1, const float* __restrict__ aux1,
    const float* __restrict__ A2, const float* __restrict__ gp2, const float* __restrict__ aux2,
    const float* __restrict__ B1a, const float* __restrict__ B1b,
    const float* __restrict__ B2a, const float* __restrict__ B2b,
    float* __restrict__ Cpart) {
  constexpr int KC = 128;
  constexpr int CT = COLW / 16;
  __shared__ short As[N_ * LDK_];
  __shared__ short Bs[COLW * LDK_];
  const int tid = threadIdx.x;
  const int colg0 = blockIdx.x * COLW;
  const int k0 = blockIdx.y * KC;
  const float* B1 = B1a;
  const float* B2 = B2a;
  int col0 = colg0;
  if (NC == 2048 && colg0 >= 1024) { B1 = B1b; B2 = B2b; col0 = colg0 - 1024; }

  const int wid  = tid >> 6;
  const int lane = tid & 63;
  const int lrow = lane & 15;
  const int lk8  = (lane >> 4) * 8;
  const int wrow0 = wid * 32;

  float4v acc[2][CT];
  #pragma unroll
  for (int a = 0; a < 2; ++a)
    #pragma unroll
    for (int b = 0; b < CT; ++b)
      acc[a][b] = (float4v){0.f, 0.f, 0.f, 0.f};

  const int arow  = tid >> 1;             // A: 2 threads/row, 64 k each
  const int ahalf = (tid & 1) * 64;

  #pragma unroll
  for (int pass = 0; pass < ((A2M >= 0) ? 2 : 1); ++pass) {
    const float* B = pass ? B2 : B1;
    if (pass) __syncthreads();
    // ---- stage A[0:128, k0:k0+128] -> bf16 (with fused combine epilogue)
    {
      short* dst = &As[arow * LDK_ + ahalf];
      #pragma unroll
      for (int j = 0; j < 16; ++j) {
        float4 v = (pass == 0)
            ? a_fetch<A1M>(A1, gp1, aux1, arow, k0 + ahalf + 4 * j)
            : a_fetch<(A2M >= 0) ? A2M : 0>(A2, gp2, aux2, arow, k0 + ahalf + 4 * j);
        *(int2*)&dst[4 * j] = make_int2(pack2(v.x, v.y), pack2(v.z, v.w));
      }
    }
    // ---- stage B[k0:k0+128, col0..col0+COLW] -> bf16 Bs[col][k]
    if (COLW == 64) {
      const int bcol = tid & 63, bkq = (tid >> 6) * 32;
      int regs[16];
      #pragma unroll
      for (int j = 0; j < 16; ++j) {
        float v0 = B[(size_t)(k0 + bkq + 2 * j) * D_ + col0 + bcol];
        float v1 = B[(size_t)(k0 + bkq + 2 * j + 1) * D_ + col0 + bcol];
        regs[j] = pack2(v0, v1);
      }
      short* dst = &Bs[bcol * LDK_ + bkq];
      *(int4*)&dst[0]  = make_int4(regs[0],  regs[1],  regs[2],  regs[3]);
      *(int4*)&dst[8]  = make_int4(regs[4],  regs[5],  regs[6],  regs[7]);
      *(int4*)&dst[16] = make_int4(regs[8],  regs[9],  regs[10], regs[11]);
      *(int4*)&dst[24] = make_int4(regs[12], regs[13], regs[14], regs[15]);
    } else {
      const int bcol = tid & 31, bkq = (tid >> 5) * 16;
      int regs[8];
      #pragma unroll
      for (int j = 0; j < 8; ++j) {
        float v0 = B[(size_t)(k0 + bkq + 2 * j) * D_ + col0 + bcol];
        float v1 = B[(size_t)(k0 + bkq + 2 * j + 1) * D_ + col0 + bcol];
        regs[j] = pack2(v0, v1);
      }
      short* dst = &Bs[bcol * LDK_ + bkq];
      *(int4*)&dst[0] = make_int4(regs[0], regs[1], regs[2], regs[3]);
      *(int4*)&dst[8] = make_int4(regs[4], regs[5], regs[6], regs[7]);
    }
    __syncthreads();
    // ---- MFMA over 4 k-chunks of 32
    #pragma unroll
    for (int kk = 0; kk < KC; kk += 32) {
      short8v a0 = *(const short8v*)&As[(wrow0 + lrow)      * LDK_ + kk + lk8];
      short8v a1 = *(const short8v*)&As[(wrow0 + 16 + lrow) * LDK_ + kk + lk8];
      #pragma unroll
      for (int ct = 0; ct < CT; ++ct) {
        short8v bf = *(const short8v*)&Bs[(ct * 16 + lrow) * LDK_ + kk + lk8];
        acc[0][ct] = __builtin_amdgcn_mfma_f32_16x16x32_bf16(a0, bf, acc[0][ct], 0, 0, 0);
        acc[1][ct] = __builtin_amdgcn_mfma_f32_16x16x32_bf16(a1, bf, acc[1][ct], 0, 0, 0);
      }
    }
  }
  float* Cp = &Cpart[(size_t)blockIdx.y * (N_ * NC)];
  const int crow = (lane >> 4) * 4;
  const int ccol = lane & 15;
  #pragma unroll
  for (int rt = 0; rt < 2; ++rt)
    #pragma unroll
    for (int ct = 0; ct < CT; ++ct)
      #pragma unroll
      for (int j = 0; j < 4; ++j) {
        int row = wrow0 + rt * 16 + crow + j;
        int col = colg0 + ct * 16 + ccol;
        Cp[(size_t)row * NC + col] = acc[rt][ct][j];
      }
}

// ---------------------------------------------------------------- LN + qk fold (device helper)
__device__ __forceinline__ void ln_qk_epilogue(int n, const float* v4, int tid,
                                               const float* __restrict__ lg,
                                               const float* __restrict__ lb,
                                               const float* __restrict__ Wq,
                                               const float* __restrict__ Wk,
                                               float* __restrict__ qkb,
                                               float* qln, float* Qp) {
  int c = tid * 4;
  float s = v4[0] + v4[1] + v4[2] + v4[3];
  float q = v4[0]*v4[0] + v4[1]*v4[1] + v4[2]*v4[2] + v4[3]*v4[3];
  __shared__ float sa[4], sb[4];
  #pragma unroll
  for (int o = 32; o; o >>= 1) { s += __shfl_xor(s, o, 64); q += __shfl_xor(q, o, 64); }
  if ((tid & 63) == 0) { sa[tid >> 6] = s; sb[tid >> 6] = q; }
  __syncthreads();
  s = sa[0] + sa[1] + sa[2] + sa[3];
  q = sb[0] + sb[1] + sb[2] + sb[3];
  float mean = s * (1.f / D_);
  float var  = q * (1.f / D_) - mean * mean;
  float rstd = rsqrtf(var + 1e-5f);
  #pragma unroll
  for (int j = 0; j < 4; ++j)
    qln[c + j] = (v4[j] - mean) * rstd * lg[c + j] + lb[c + j];
  __syncthreads();
  #pragma unroll
  for (int j = 0; j < 4; ++j) {
    int idx = tid + j * 256; int h = idx >> 6, e = idx & 63;
    float acc = 0.f;
    for (int d = 0; d < DH_; ++d)
      acc += qln[(h << 6) + d] * Wq[((size_t)(h << 6) + d) * DH_ + e];
    Qp[idx] = acc;
  }
  __syncthreads();
  #pragma unroll
  for (int j = 0; j < 4; ++j) {
    int idx = tid + j * 256; int h = idx >> 6, d = idx & 63;
    float acc = 0.f;
    for (int e = 0; e < DH_; ++e)
      acc += Wk[((size_t)(h << 6) + d) * DH_ + e] * Qp[(h << 6) + e];
    qkb[(size_t)n * D_ + idx] = acc * 0.03125f;
  }
}

// ---------------------------------------------------------------- embed combine
__global__ __launch_bounds__(256) void comb_embed_lnqk(const float* __restrict__ Cp,
                                                       const float* __restrict__ bias,
                                                       const float* __restrict__ lg,
                                                       const float* __restrict__ lb,
                                                       const float* __restrict__ Wq,
                                                       const float* __restrict__ Wk,
                                                       float* __restrict__ hcur,
                                                       float* __restrict__ out_li,
                                                       float* __restrict__ qkb) {
  int n = blockIdx.x, tid = threadIdx.x, c = tid * 4;
  __shared__ float qln[D_], Qp[D_];
  float4 a4 = {0.f, 0.f, 0.f, 0.f};
  #pragma unroll
  for (int s = 0; s < KS_; ++s) {
    float4 p = *(const float4*)&Cp[(size_t)s * (N_ * D_) + (size_t)n * D_ + c];
    a4.x += p.x; a4.y += p.y; a4.z += p.z; a4.w += p.w;
  }
  float4 b4 = *(const float4*)&bias[c];
  float v[4] = {fmaxf(a4.x + b4.x, 0.f), fmaxf(a4.y + b4.y, 0.f),
                fmaxf(a4.z + b4.z, 0.f), fmaxf(a4.w + b4.w, 0.f)};
  *(float4*)&hcur[(size_t)n * D_ + c] = *(float4*)v;
  *(float4*)&out_li[((size_t)n * NB_ + 0) * D_ + c] = *(float4*)v;
  ln_qk_epilogue(n, v, tid, lg, lb, Wq, Wk, qkb, qln, Qp);
}

// ---------------------------------------------------------------- streaming attention (round-9 form)
__global__ __launch_bounds__(256) void attn_stream(
    const float* __restrict__ mem, const float* __restrict__ pos,
    const int* __restrict__ mask, const int* __restrict__ midx,
    const float* __restrict__ qkv, const float* __restrict__ lng,
    const float* __restrict__ lnb, int blk,
    float* __restrict__ pav, float* __restrict__ pm, float* __restrict__ ps)
{
  const int n    = blockIdx.y;
  const int w    = threadIdx.x >> 6;
  const int lane = threadIdx.x & 63;
  const int vc   = blockIdx.x * 4 + w;
  const int l0   = vc * (L_ / NCV_);
  const int d0   = lane * 16;

  float g[16], bv[16], qv[16];
  #pragma unroll
  for (int j = 0; j < 4; ++j) {
    float4 t0 = *(const float4*)&lng[d0 + 4 * j];
    g[4*j+0] = t0.x; g[4*j+1] = t0.y; g[4*j+2] = t0.z; g[4*j+3] = t0.w;
    float4 t1 = *(const float4*)&lnb[d0 + 4 * j];
    bv[4*j+0] = t1.x; bv[4*j+1] = t1.y; bv[4*j+2] = t1.z; bv[4*j+3] = t1.w;
    float4 t2 = *(const float4*)&qkv[(size_t)n * D_ + d0 + 4 * j];
    qv[4*j+0] = t2.x; qv[4*j+1] = t2.y; qv[4*j+2] = t2.z; qv[4*j+3] = t2.w;
  }
  float m_run = -INFINITY, s_run = 0.f;
  float av[16];
  #pragma unroll
  for (int j = 0; j < 16; ++j) av[j] = 0.f;

  for (int l = l0; l < l0 + (L_ / NCV_); ++l) {
    if (mask[(size_t)n * L_ + l] == 0) continue;
    const float* xr = &mem[(((size_t)n * L_ + l) * NB_ + blk) * D_ + d0];
    const int tt = midx[(size_t)n * L_ + l];
    const float* pr = &pos[(size_t)tt * D_ + d0];
    float xv[16];
    #pragma unroll
    for (int j = 0; j < 4; ++j) {
      float4 a = *(const float4*)&xr[4 * j];
      float4 p = *(const float4*)&pr[4 * j];
      xv[4*j+0] = a.x + p.x; xv[4*j+1] = a.y + p.y;
      xv[4*j+2] = a.z + p.z; xv[4*j+3] = a.w + p.w;
    }
    float s1 = 0.f, s2 = 0.f;
    #pragma unroll
    for (int j = 0; j < 16; ++j) { s1 += xv[j]; s2 += xv[j] * xv[j]; }
    #pragma unroll
    for (int o = 32; o; o >>= 1) { s1 += __shfl_xor(s1, o, 64); s2 += __shfl_xor(s2, o, 64); }
    float mean = s1 * (1.f / D_);
    float var  = s2 * (1.f / D_) - mean * mean;
    float rstd = rsqrtf(var + 1e-5f);
    float e = 0.f;
    float y[16];
    #pragma unroll
    for (int j = 0; j < 16; ++j) {
      y[j] = (xv[j] - mean) * rstd * g[j] + bv[j];
      e += y[j] * qv[j];
    }
    e += __shfl_xor(e, 1, 64);
    e += __shfl_xor(e, 2, 64);
    float mn = fmaxf(m_run, e);
    float al = __expf(m_run - mn);
    float pw = __expf(e - mn);
    s_run = s_run * al + pw;
    #pragma unroll
    for (int j = 0; j < 16; ++j) av[j] = av[j] * al + pw * y[j];
    m_run = mn;
  }
  size_t base = ((size_t)n * NCV_ + vc) * D_ + d0;
  #pragma unroll
  for (int j = 0; j < 16; ++j) pav[base + j] = av[j];
  if ((lane & 3) == 0) {
    size_t mb = ((size_t)n * NCV_ + vc) * H_ + (lane >> 2);
    pm[mb] = m_run;
    ps[mb] = s_run;
  }
}

// ---------------------------------------------------------------- merge chunks + V-projection -> tb
__global__ __launch_bounds__(256) void attn_fin(const float* __restrict__ pav,
                                                const float* __restrict__ pm,
                                                const float* __restrict__ ps,
                                                const float* __restrict__ Wv,
                                                float* __restrict__ tb) {
  int n = blockIdx.x, tid = threadIdx.x;
  int d0 = tid * 4; int h = tid >> 4;
  float M = -INFINITY;
  for (int c = 0; c < NCV_; ++c) M = fmaxf(M, pm[((size_t)n * NCV_ + c) * H_ + h]);
  float S = 0.f, a0 = 0.f, a1 = 0.f, a2 = 0.f, a3 = 0.f;
  if (M > -INFINITY) {
    for (int c = 0; c < NCV_; ++c) {
      float mc = pm[((size_t)n * NCV_ + c) * H_ + h];
      if (mc == -INFINITY) continue;
      float wgt = __expf(mc - M);
      S += ps[((size_t)n * NCV_ + c) * H_ + h] * wgt;
      size_t ab = ((size_t)n * NCV_ + c) * D_ + d0;
      float4 v = *(const float4*)&pav[ab];
      a0 += v.x * wgt; a1 += v.y * wgt; a2 += v.z * wgt; a3 += v.w * wgt;
    }
  }
  float inv = (S > 0.f) ? 1.f / S : 0.f;
  __shared__ float att[D_];
  att[d0 + 0] = a0 * inv; att[d0 + 1] = a1 * inv;
  att[d0 + 2] = a2 * inv; att[d0 + 3] = a3 * inv;
  __syncthreads();
  #pragma unroll
  for (int j = 0; j < 4; ++j) {
    int idx = tid + j * 256; int hh = idx >> 6, e = idx & 63;
    float acc = 0.f;
    for (int d = 0; d < DH_; ++d)
      acc += att[(hh << 6) + d] * Wv[((size_t)(hh << 6) + d) * DH_ + e];
    tb[(size_t)n * D_ + idx] = acc;
  }
}

// ---------------------------------------------------------------- GRU h combine + LN2 (z recomputed from RZ partials)
__global__ __launch_bounds__(256) void comb_h_ln(const float* __restrict__ CpH,
                                                 const float* __restrict__ gpRZ,
                                                 const float* __restrict__ bg,
                                                 const float* __restrict__ xb,
                                                 const float* __restrict__ lg,
                                                 const float* __restrict__ lb,
                                                 float* __restrict__ h1,
                                                 float* __restrict__ hl) {
  int n = blockIdx.x, tid = threadIdx.x, c = tid * 4;
  float4 a4 = {0.f, 0.f, 0.f, 0.f}, zz = {0.f, 0.f, 0.f, 0.f};
  #pragma unroll
  for (int ss = 0; ss < KS_; ++ss) {
    float4 p = *(const float4*)&CpH[(size_t)ss * (N_ * D_) + (size_t)n * D_ + c];
    a4.x += p.x; a4.y += p.y; a4.z += p.z; a4.w += p.w;
    float4 zp = *(const float4*)&gpRZ[(size_t)ss * (N_ * 2048) + (size_t)n * 2048 + 1024 + c];
    zz.x += zp.x; zz.y += zp.y; zz.z += zp.z; zz.w += zp.w;
  }
  float4 g4 = *(const float4*)&bg[c];
  float4 z4;
  z4.x = 1.f / (1.f + __expf(-(zz.x - g4.x)));
  z4.y = 1.f / (1.f + __expf(-(zz.y - g4.y)));
  z4.z = 1.f / (1.f + __expf(-(zz.z - g4.z)));
  z4.w = 1.f / (1.f + __expf(-(zz.w - g4.w)));
  float4 x4 = *(const float4*)&xb[(size_t)n * D_ + c];
  float v[4];
  v[0] = (1.f - z4.x) * x4.x + z4.x * tanhf(a4.x);
  v[1] = (1.f - z4.y) * x4.y + z4.y * tanhf(a4.y);
  v[2] = (1.f - z4.z) * x4.z + z4.z * tanhf(a4.z);
  v[3] = (1.f - z4.w) * x4.w + z4.w * tanhf(a4.w);
  *(float4*)&h1[(size_t)n * D_ + c] = *(float4*)v;
  float s = v[0] + v[1] + v[2] + v[3];
  float q = v[0]*v[0] + v[1]*v[1] + v[2]*v[2] + v[3]*v[3];
  __shared__ float sa[4], sb[4];
  #pragma unroll
  for (int o = 32; o; o >>= 1) { s += __shfl_xor(s, o, 64); q += __shfl_xor(q, o, 64); }
  if ((tid & 63) == 0) { sa[tid >> 6] = s; sb[tid >> 6] = q; }
  __syncthreads();
  s = sa[0] + sa[1] + sa[2] + sa[3];
  q = sb[0] + sb[1] + sb[2] + sb[3];
  float mean = s * (1.f / D_);
  float var  = q * (1.f / D_) - mean * mean;
  float rstd = rsqrtf(var + 1e-5f);
  #pragma unroll
  for (int j = 0; j < 4; ++j)
    hl[(size_t)n * D_ + c + j] = (v[j] - mean) * rstd * lg[c + j] + lb[c + j];
}

// ---------------------------------------------------------------- GRU2 h combine -> hcur, out, optional LN1+qk(next)
__global__ __launch_bounds__(256) void comb_h2_lnqk(const float* __restrict__ CpH,
                                                    const float* __restrict__ gpRZ,
                                                    const float* __restrict__ bg,
                                                    const float* __restrict__ xb,
                                                    const float* __restrict__ lg,
                                                    const float* __restrict__ lb,
                                                    const float* __restrict__ Wq,
                                                    const float* __restrict__ Wk,
                                                    float* __restrict__ hcur,
                                                    float* __restrict__ outp,
                                                    int slot,
                                                    float* __restrict__ qkb) {
  int n = blockIdx.x, tid = threadIdx.x, c = tid * 4;
  __shared__ float qln[D_], Qp[D_];
  float4 a4 = {0.f, 0.f, 0.f, 0.f}, zz = {0.f, 0.f, 0.f, 0.f};
  #pragma unroll
  for (int ss = 0; ss < KS_; ++ss) {
    float4 p = *(const float4*)&CpH[(size_t)ss * (N_ * D_) + (size_t)n * D_ + c];
    a4.x += p.x; a4.y += p.y; a4.z += p.z; a4.w += p.w;
    float4 zp = *(const float4*)&gpRZ[(size_t)ss * (N_ * 2048) + (size_t)n * 2048 + 1024 + c];
    zz.x += zp.x; zz.y += zp.y; zz.z += zp.z; zz.w += zp.w;
  }
  float4 g4 = *(const float4*)&bg[c];
  float4 z4;
  z4.x = 1.f / (1.f + __expf(-(zz.x - g4.x)));
  z4.y = 1.f / (1.f + __expf(-(zz.y - g4.y)));
  z4.z = 1.f / (1.f + __expf(-(zz.z - g4.z)));
  z4.w = 1.f / (1.f + __expf(-(zz.w - g4.w)));
  float4 x4 = *(const float4*)&xb[(size_t)n * D_ + c];
  float v[4];
  v[0] = (1.f - z4.x) * x4.x + z4.x * tanhf(a4.x);
  v[1] = (1.f - z4.y) * x4.y + z4.y * tanhf(a4.y);
  v[2] = (1.f - z4.z) * x4.z + z4.z * tanhf(a4.z);
  v[3] = (1.f - z4.w) * x4.w + z4.w * tanhf(a4.w);
  *(float4*)&hcur[(size_t)n * D_ + c] = *(float4*)v;
  size_t bi = (slot >= 0) ? (((size_t)n * NB_ + slot) * D_ + c)
                          : ((size_t)n * D_ + c);
  *(float4*)&outp[bi] = *(float4*)v;
  if (Wq != nullptr)
    ln_qk_epilogue(n, v, tid, lg, lb, Wq, Wk, qkb, qln, Qp);
}

// ----------------------------------------------------------------
extern "C" void kernel_launch(void* const* d_in, const int* in_sizes, int n_in,
                              void* d_out, int out_size, void* d_ws, size_t ws_size,
                              hipStream_t stream) {
  const float* x    = (const float*)d_in[0];
  const float* mem  = (const float*)d_in[1];
  const int*   mask = (const int*)d_in[2];
  const int*   midx = (const int*)d_in[3];
  const float* We   = (const float*)d_in[5];
  const float* be   = (const float*)d_in[6];
  const float* Wq   = (const float*)d_in[7];
  const float* Wk   = (const float*)d_in[8];
  const float* Wv   = (const float*)d_in[9];
  const float* Wo   = (const float*)d_in[10];
  const float* bo   = (const float*)d_in[11];
  const float* Wfc  = (const float*)d_in[12];
  const float* bfc  = (const float*)d_in[13];
  const float* ln1g = (const float*)d_in[14];
  const float* ln1b = (const float*)d_in[15];
  const float* ln2g = (const float*)d_in[16];
  const float* ln2b = (const float*)d_in[17];
  const float* lnkg = (const float*)d_in[18];
  const float* lnkb = (const float*)d_in[19];
  const float* g1w[7]; for (int j = 0; j < 7; ++j) g1w[j] = (const float*)d_in[20 + j];
  const float* g2w[7]; for (int j = 0; j < 7; ++j) g2w[j] = (const float*)d_in[27 + j];
  float* out = (float*)d_out;
  float* out_li = out + (size_t)N_ * D_;

  float* ws   = (float*)d_ws;
  float* pos  = ws; ws += (size_t)T_ * D_;
  float* hcur = ws; ws += N_ * D_;
  float* qkb  = ws; ws += N_ * D_;
  float* tb   = ws; ws += N_ * D_;
  float* h1   = ws; ws += N_ * D_;
  float* hl   = ws; ws += N_ * D_;
  float* P1   = ws; ws += (size_t)KS_ * N_ * 1024;    // 4 MB  (Wo / FC partials)
  float* P2   = ws; ws += (size_t)KS_ * N_ * 2048;    // 8 MB  (RZ partials)
  float* P3   = ws; ws += (size_t)KS_ * N_ * 1024;    // 4 MB  (h partials)
  float* pav  = ws; ws += (size_t)N_ * NCV_ * D_;     // 16 MB
  float* pm   = ws; ws += (size_t)N_ * NCV_ * H_;
  float* ps   = ws; ws += (size_t)N_ * NCV_ * H_;

  const dim3 gp(32, KS_);            // 256 blocks, 256 threads
  const dim3 at_grid(NCV_ / 4, N_);  // 1024 blocks

  pos_kernel<<<T_, 512, 0, stream>>>(pos);

  gemm_part_t<32, 1024, 0, -1><<<gp, 256, 0, stream>>>(
      x, nullptr, nullptr, nullptr, nullptr, nullptr,
      We, nullptr, nullptr, nullptr, P1);
  comb_embed_lnqk<<<N_, 256, 0, stream>>>(P1, be, ln1g, ln1b, Wq, Wk, hcur, out_li, qkb);

  for (int i = 0; i < NB_; ++i) {
    size_t oD  = (size_t)i * D_;
    size_t oDD = (size_t)i * D_ * D_;
    size_t oH  = (size_t)i * H_ * DH_ * DH_;

    attn_stream<<<at_grid, 256, 0, stream>>>(mem, pos, mask, midx, qkb,
                                             lnkg + oD, lnkb + oD, i, pav, pm, ps);
    attn_fin<<<N_, 256, 0, stream>>>(pav, pm, ps, Wv + oH, tb);

    // Wo partials (ao never materialized)
    gemm_part_t<32, 1024, 0, -1><<<gp, 256, 0, stream>>>(
        tb, nullptr, nullptr, nullptr, nullptr, nullptr,
        Wo + oDD, nullptr, nullptr, nullptr, P1);

    // GRU1 RZ: A1 = ao (fused from P1 + bo), A2 = hcur
    gemm_part_t<64, 2048, 1, 0><<<gp, 256, 0, stream>>>(
        nullptr, P1, bo + oD, hcur, nullptr, nullptr,
        g1w[0] + oDD, g1w[2] + oDD, g1w[1] + oDD, g1w[3] + oDD, P2);
    // GRU1 h: A1 = ao (fused), A2 = rq (fused from P2 cols<1024, * hcur)
    gemm_part_t<32, 1024, 1, 3><<<gp, 256, 0, stream>>>(
        nullptr, P1, bo + oD, nullptr, P2, hcur,
        g1w[4] + oDD, nullptr, g1w[5] + oDD, nullptr, P3);
    comb_h_ln<<<N_, 256, 0, stream>>>(P3, P2, g1w[6] + oD, hcur,
                                      ln2g + oD, ln2b + oD, h1, hl);

    // FC partials (fwd never materialized)
    gemm_part_t<32, 1024, 0, -1><<<gp, 256, 0, stream>>>(
        hl, nullptr, nullptr, nullptr, nullptr, nullptr,
        Wfc + oDD, nullptr, nullptr, nullptr, P1);

    // GRU2 RZ: A1 = fwd (fused relu from P1 + bfc), A2 = h1
    gemm_part_t<64, 2048, 2, 0><<<gp, 256, 0, stream>>>(
        nullptr, P1, bfc + oD, h1, nullptr, nullptr,
        g2w[0] + oDD, g2w[2] + oDD, g2w[1] + oDD, g2w[3] + oDD, P2);
    // GRU2 h: A1 = fwd (fused), A2 = rq2 (fused from P2, * h1)
    gemm_part_t<32, 1024, 2, 3><<<gp, 256, 0, stream>>>(
        nullptr, P1, bfc + oD, nullptr, P2, h1,
        g2w[4] + oDD, nullptr, g2w[5] + oDD, nullptr, P3);

    bool last = (i == NB_ - 1);
    float* outp = last ? out : out_li;
    int slot = last ? -1 : (i + 1);
    const float* nWq = last ? nullptr : (Wq + oH + H_ * DH_ * DH_);
    const float* nWk = last ? nullptr : (Wk + oH + H_ * DH_ * DH_);
    const float* nlg = last ? nullptr : (ln1g + oD + D_);
    const float* nlb = last ? nullptr : (ln1b + oD + D_);
    comb_h2_lnqk<<<N_, 256, 0, stream>>>(P3, P2, g2w[6] + oD, h1, nlg, nlb,
                                         nWq, nWk, hcur, outp, slot, qkb);
  }
}

// Round 14
// 987.562 us; speedup vs baseline: 1.5688x; 1.5688x over previous
//
#include <hip/hip_runtime.h>
#include <hip/hip_bf16.h>

#define N_   128
#define L_   512
#define NB_  4
#define D_   1024
#define H_   16
#define DH_  64
#define IN_  1024
#define T_   512

#define KS_  8       // GEMM K-splits (Kc = 128)
#define NCV_ 32      // attention chunks per sample (16 rows each)

typedef __attribute__((ext_vector_type(8))) short short8v;
typedef __attribute__((ext_vector_type(4))) float float4v;

__device__ __forceinline__ short f2bf(float f) {             // RNE f32->bf16
  unsigned u = __float_as_uint(f);
  u += 0x7FFFu + ((u >> 16) & 1u);
  return (short)(u >> 16);
}
__device__ __forceinline__ int pack2(float a, float b) {
  return (int)(unsigned short)f2bf(a) | ((int)f2bf(b) << 16);
}

// ---------------------------------------------------------------- pos table
__global__ __launch_bounds__(512) void pos_kernel(float* __restrict__ pos) {
  int t = blockIdx.x;
  int j = threadIdx.x;
  float seq = (float)(T_ - 1 - t);
  float ex  = (float)(2 * j) * (1.0f / (float)D_);
  float inv = expf(-ex * 9.210340371976184f);
  float si  = seq * inv;
  pos[(size_t)t * D_ + j]        = sinf(si);
  pos[(size_t)t * D_ + 512 + j]  = cosf(si);
}

// ---------------------------------------------------------------- MFMA split-K GEMM partials
// 256 threads = 4 waves; Kc=128; grid (32 col-tiles, 8 k-splits) = 256 blocks.
#define LDK_ 136   // padded k-row (shorts)
template<int COLW, int NC, bool HAS2>
__global__ __launch_bounds__(256) void gemm_part_t(const float* __restrict__ A1,
                                                   const float* __restrict__ B1a,
                                                   const float* __restrict__ B1b,
                                                   const float* __restrict__ A2,
                                                   const float* __restrict__ B2a,
                                                   const float* __restrict__ B2b,
                                                   float* __restrict__ Cpart) {
  constexpr int KC = 128;
  constexpr int CT = COLW / 16;
  __shared__ short As[N_ * LDK_];
  __shared__ short Bs[COLW * LDK_];
  const int tid = threadIdx.x;
  const int colg0 = blockIdx.x * COLW;
  const int k0 = blockIdx.y * KC;
  const float* B1 = B1a;
  const float* B2 = B2a;
  int col0 = colg0;
  if (NC == 2048 && colg0 >= 1024) { B1 = B1b; B2 = B2b; col0 = colg0 - 1024; }

  const int wid  = tid >> 6;
  const int lane = tid & 63;
  const int lrow = lane & 15;
  const int lk8  = (lane >> 4) * 8;
  const int wrow0 = wid * 32;

  float4v acc[2][CT];
  #pragma unroll
  for (int a = 0; a < 2; ++a)
    #pragma unroll
    for (int b = 0; b < CT; ++b)
      acc[a][b] = (float4v){0.f, 0.f, 0.f, 0.f};

  const int arow  = tid >> 1;             // A: 2 threads/row, 64 k each
  const int ahalf = (tid & 1) * 64;

  #pragma unroll
  for (int pass = 0; pass < (HAS2 ? 2 : 1); ++pass) {
    const float* A = pass ? A2 : A1;
    const float* B = pass ? B2 : B1;
    if (pass) __syncthreads();
    // ---- stage A[0:128, k0:k0+128] -> bf16
    {
      const float* ap = &A[(size_t)arow * D_ + k0 + ahalf];
      short* dst = &As[arow * LDK_ + ahalf];
      #pragma unroll
      for (int j = 0; j < 16; ++j) {
        float4 v = *(const float4*)&ap[4 * j];
        *(int2*)&dst[4 * j] = make_int2(pack2(v.x, v.y), pack2(v.z, v.w));
      }
    }
    // ---- stage B[k0:k0+128, col0:col0+COLW] -> bf16 Bs[col][k]
    if (COLW == 64) {
      const int bcol = tid & 63, bkq = (tid >> 6) * 32;
      int regs[16];
      #pragma unroll
      for (int j = 0; j < 16; ++j) {
        float v0 = B[(size_t)(k0 + bkq + 2 * j) * D_ + col0 + bcol];
        float v1 = B[(size_t)(k0 + bkq + 2 * j + 1) * D_ + col0 + bcol];
        regs[j] = pack2(v0, v1);
      }
      short* dst = &Bs[bcol * LDK_ + bkq];
      *(int4*)&dst[0]  = make_int4(regs[0],  regs[1],  regs[2],  regs[3]);
      *(int4*)&dst[8]  = make_int4(regs[4],  regs[5],  regs[6],  regs[7]);
      *(int4*)&dst[16] = make_int4(regs[8],  regs[9],  regs[10], regs[11]);
      *(int4*)&dst[24] = make_int4(regs[12], regs[13], regs[14], regs[15]);
    } else {
      const int bcol = tid & 31, bkq = (tid >> 5) * 16;
      int regs[8];
      #pragma unroll
      for (int j = 0; j < 8; ++j) {
        float v0 = B[(size_t)(k0 + bkq + 2 * j) * D_ + col0 + bcol];
        float v1 = B[(size_t)(k0 + bkq + 2 * j + 1) * D_ + col0 + bcol];
        regs[j] = pack2(v0, v1);
      }
      short* dst = &Bs[bcol * LDK_ + bkq];
      *(int4*)&dst[0] = make_int4(regs[0], regs[1], regs[2], regs[3]);
      *(int4*)&dst[8] = make_int4(regs[4], regs[5], regs[6], regs[7]);
    }
    __syncthreads();
    // ---- MFMA over 4 k-chunks of 32
    #pragma unroll
    for (int kk = 0; kk < KC; kk += 32) {
      short8v a0 = *(const short8v*)&As[(wrow0 + lrow)      * LDK_ + kk + lk8];
      short8v a1 = *(const short8v*)&As[(wrow0 + 16 + lrow) * LDK_ + kk + lk8];
      #pragma unroll
      for (int ct = 0; ct < CT; ++ct) {
        short8v bf = *(const short8v*)&Bs[(ct * 16 + lrow) * LDK_ + kk + lk8];
        acc[0][ct] = __builtin_amdgcn_mfma_f32_16x16x32_bf16(a0, bf, acc[0][ct], 0, 0, 0);
        acc[1][ct] = __builtin_amdgcn_mfma_f32_16x16x32_bf16(a1, bf, acc[1][ct], 0, 0, 0);
      }
    }
  }
  float* Cp = &Cpart[(size_t)blockIdx.y * (N_ * NC)];
  const int crow = (lane >> 4) * 4;
  const int ccol = lane & 15;
  #pragma unroll
  for (int rt = 0; rt < 2; ++rt)
    #pragma unroll
    for (int ct = 0; ct < CT; ++ct)
      #pragma unroll
      for (int j = 0; j < 4; ++j) {
        int row = wrow0 + rt * 16 + crow + j;
        int col = colg0 + ct * 16 + ccol;
        Cp[(size_t)row * NC + col] = acc[rt][ct][j];
      }
}

// ---------------------------------------------------------------- LN + qk fold (device helper)
__device__ __forceinline__ void ln_qk_epilogue(int n, const float* v4, int tid,
                                               const float* __restrict__ lg,
                                               const float* __restrict__ lb,
                                               const float* __restrict__ Wq,
                                               const float* __restrict__ Wk,
                                               float* __restrict__ qkb,
                                               float* qln, float* Qp) {
  int c = tid * 4;
  float s = v4[0] + v4[1] + v4[2] + v4[3];
  float q = v4[0]*v4[0] + v4[1]*v4[1] + v4[2]*v4[2] + v4[3]*v4[3];
  __shared__ float sa[4], sb[4];
  #pragma unroll
  for (int o = 32; o; o >>= 1) { s += __shfl_xor(s, o, 64); q += __shfl_xor(q, o, 64); }
  if ((tid & 63) == 0) { sa[tid >> 6] = s; sb[tid >> 6] = q; }
  __syncthreads();
  s = sa[0] + sa[1] + sa[2] + sa[3];
  q = sb[0] + sb[1] + sb[2] + sb[3];
  float mean = s * (1.f / D_);
  float var  = q * (1.f / D_) - mean * mean;
  float rstd = rsqrtf(var + 1e-5f);
  #pragma unroll
  for (int j = 0; j < 4; ++j)
    qln[c + j] = (v4[j] - mean) * rstd * lg[c + j] + lb[c + j];
  __syncthreads();
  #pragma unroll
  for (int j = 0; j < 4; ++j) {
    int idx = tid + j * 256; int h = idx >> 6, e = idx & 63;
    float acc = 0.f;
    for (int d = 0; d < DH_; ++d)
      acc += qln[(h << 6) + d] * Wq[((size_t)(h << 6) + d) * DH_ + e];
    Qp[idx] = acc;
  }
  __syncthreads();
  #pragma unroll
  for (int j = 0; j < 4; ++j) {
    int idx = tid + j * 256; int h = idx >> 6, d = idx & 63;
    float acc = 0.f;
    for (int e = 0; e < DH_; ++e)
      acc += Wk[((size_t)(h << 6) + d) * DH_ + e] * Qp[(h << 6) + e];
    qkb[(size_t)n * D_ + idx] = acc * 0.03125f;
  }
}

// ---------------------------------------------------------------- embed combine
__global__ __launch_bounds__(256) void comb_embed_lnqk(const float* __restrict__ Cp,
                                                       const float* __restrict__ bias,
                                                       const float* __restrict__ lg,
                                                       const float* __restrict__ lb,
                                                       const float* __restrict__ Wq,
                                                       const float* __restrict__ Wk,
                                                       float* __restrict__ hcur,
                                                       float* __restrict__ out_li,
                                                       float* __restrict__ qkb) {
  int n = blockIdx.x, tid = threadIdx.x, c = tid * 4;
  __shared__ float qln[D_], Qp[D_];
  float4 a4 = {0.f, 0.f, 0.f, 0.f};
  #pragma unroll
  for (int s = 0; s < KS_; ++s) {
    float4 p = *(const float4*)&Cp[(size_t)s * (N_ * D_) + (size_t)n * D_ + c];
    a4.x += p.x; a4.y += p.y; a4.z += p.z; a4.w += p.w;
  }
  float4 b4 = *(const float4*)&bias[c];
  float v[4] = {fmaxf(a4.x + b4.x, 0.f), fmaxf(a4.y + b4.y, 0.f),
                fmaxf(a4.z + b4.z, 0.f), fmaxf(a4.w + b4.w, 0.f)};
  *(float4*)&hcur[(size_t)n * D_ + c] = *(float4*)v;
  *(float4*)&out_li[((size_t)n * NB_ + 0) * D_ + c] = *(float4*)v;
  ln_qk_epilogue(n, v, tid, lg, lb, Wq, Wk, qkb, qln, Qp);
}

// ---------------------------------------------------------------- streaming attention (NT loads on memories)
__global__ __launch_bounds__(256) void attn_stream(
    const float* __restrict__ mem, const float* __restrict__ pos,
    const int* __restrict__ mask, const int* __restrict__ midx,
    const float* __restrict__ qkv, const float* __restrict__ lng,
    const float* __restrict__ lnb, int blk,
    float* __restrict__ pav, float* __restrict__ pm, float* __restrict__ ps)
{
  const int n    = blockIdx.y;
  const int w    = threadIdx.x >> 6;
  const int lane = threadIdx.x & 63;
  const int vc   = blockIdx.x * 4 + w;
  const int l0   = vc * (L_ / NCV_);
  const int d0   = lane * 16;

  float g[16], bv[16], qv[16];
  #pragma unroll
  for (int j = 0; j < 4; ++j) {
    float4 t0 = *(const float4*)&lng[d0 + 4 * j];
    g[4*j+0] = t0.x; g[4*j+1] = t0.y; g[4*j+2] = t0.z; g[4*j+3] = t0.w;
    float4 t1 = *(const float4*)&lnb[d0 + 4 * j];
    bv[4*j+0] = t1.x; bv[4*j+1] = t1.y; bv[4*j+2] = t1.z; bv[4*j+3] = t1.w;
    float4 t2 = *(const float4*)&qkv[(size_t)n * D_ + d0 + 4 * j];
    qv[4*j+0] = t2.x; qv[4*j+1] = t2.y; qv[4*j+2] = t2.z; qv[4*j+3] = t2.w;
  }
  float m_run = -INFINITY, s_run = 0.f;
  float av[16];
  #pragma unroll
  for (int j = 0; j < 16; ++j) av[j] = 0.f;

  for (int l = l0; l < l0 + (L_ / NCV_); ++l) {
    if (mask[(size_t)n * L_ + l] == 0) continue;
    const float* xr = &mem[(((size_t)n * L_ + l) * NB_ + blk) * D_ + d0];
    const int tt = midx[(size_t)n * L_ + l];
    const float* pr = &pos[(size_t)tt * D_ + d0];
    float xv[16];
    #pragma unroll
    for (int j = 0; j < 4; ++j) {
      float4v a = __builtin_nontemporal_load((const float4v*)&xr[4 * j]);   // read-once stream
      float4 p = *(const float4*)&pr[4 * j];
      xv[4*j+0] = a[0] + p.x; xv[4*j+1] = a[1] + p.y;
      xv[4*j+2] = a[2] + p.z; xv[4*j+3] = a[3] + p.w;
    }
    float s1 = 0.f, s2 = 0.f;
    #pragma unroll
    for (int j = 0; j < 16; ++j) { s1 += xv[j]; s2 += xv[j] * xv[j]; }
    #pragma unroll
    for (int o = 32; o; o >>= 1) { s1 += __shfl_xor(s1, o, 64); s2 += __shfl_xor(s2, o, 64); }
    float mean = s1 * (1.f / D_);
    float var  = s2 * (1.f / D_) - mean * mean;
    float rstd = rsqrtf(var + 1e-5f);
    float e = 0.f;
    float y[16];
    #pragma unroll
    for (int j = 0; j < 16; ++j) {
      y[j] = (xv[j] - mean) * rstd * g[j] + bv[j];
      e += y[j] * qv[j];
    }
    e += __shfl_xor(e, 1, 64);
    e += __shfl_xor(e, 2, 64);
    float mn = fmaxf(m_run, e);
    float al = __expf(m_run - mn);
    float pw = __expf(e - mn);
    s_run = s_run * al + pw;
    #pragma unroll
    for (int j = 0; j < 16; ++j) av[j] = av[j] * al + pw * y[j];
    m_run = mn;
  }
  size_t base = ((size_t)n * NCV_ + vc) * D_ + d0;
  #pragma unroll
  for (int j = 0; j < 16; ++j) pav[base + j] = av[j];
  if ((lane & 3) == 0) {
    size_t mb = ((size_t)n * NCV_ + vc) * H_ + (lane >> 2);
    pm[mb] = m_run;
    ps[mb] = s_run;
  }
}

// ---------------------------------------------------------------- merge chunks + V-projection -> tb
__global__ __launch_bounds__(256) void attn_fin(const float* __restrict__ pav,
                                                const float* __restrict__ pm,
                                                const float* __restrict__ ps,
                                                const float* __restrict__ Wv,
                                                float* __restrict__ tb) {
  int n = blockIdx.x, tid = threadIdx.x;
  int d0 = tid * 4; int h = tid >> 4;
  float M = -INFINITY;
  for (int c = 0; c < NCV_; ++c) M = fmaxf(M, pm[((size_t)n * NCV_ + c) * H_ + h]);
  float S = 0.f, a0 = 0.f, a1 = 0.f, a2 = 0.f, a3 = 0.f;
  if (M > -INFINITY) {
    for (int c = 0; c < NCV_; ++c) {
      float mc = pm[((size_t)n * NCV_ + c) * H_ + h];
      if (mc == -INFINITY) continue;
      float wgt = __expf(mc - M);
      S += ps[((size_t)n * NCV_ + c) * H_ + h] * wgt;
      size_t ab = ((size_t)n * NCV_ + c) * D_ + d0;
      float4 v = *(const float4*)&pav[ab];
      a0 += v.x * wgt; a1 += v.y * wgt; a2 += v.z * wgt; a3 += v.w * wgt;
    }
  }
  float inv = (S > 0.f) ? 1.f / S : 0.f;
  __shared__ float att[D_];
  att[d0 + 0] = a0 * inv; att[d0 + 1] = a1 * inv;
  att[d0 + 2] = a2 * inv; att[d0 + 3] = a3 * inv;
  __syncthreads();
  #pragma unroll
  for (int j = 0; j < 4; ++j) {
    int idx = tid + j * 256; int hh = idx >> 6, e = idx & 63;
    float acc = 0.f;
    for (int d = 0; d < DH_; ++d)
      acc += att[(hh << 6) + d] * Wv[((size_t)(hh << 6) + d) * DH_ + e];
    tb[(size_t)n * D_ + idx] = acc;
  }
}

// ---------------------------------------------------------------- elementwise combine (float4)
__global__ __launch_bounds__(256) void comb_ew(const float* __restrict__ Cp,
                                               const float* __restrict__ bias,
                                               float* __restrict__ out, int mode) {
  int base = (blockIdx.x * 256 + threadIdx.x) * 4;
  int col = base & (D_ - 1);
  float4 a4 = {0.f, 0.f, 0.f, 0.f};
  #pragma unroll
  for (int s = 0; s < KS_; ++s) {
    float4 p = *(const float4*)&Cp[(size_t)s * (N_ * D_) + base];
    a4.x += p.x; a4.y += p.y; a4.z += p.z; a4.w += p.w;
  }
  float4 b4 = *(const float4*)&bias[col];
  a4.x += b4.x; a4.y += b4.y; a4.z += b4.z; a4.w += b4.w;
  if (mode == 0) {
    a4.x = fmaxf(a4.x, 0.f); a4.y = fmaxf(a4.y, 0.f);
    a4.z = fmaxf(a4.z, 0.f); a4.w = fmaxf(a4.w, 0.f);
  }
  *(float4*)&out[base] = a4;
}

// ---------------------------------------------------------------- GRU r,z combine (float4)
__global__ __launch_bounds__(256) void comb_rz(const float* __restrict__ Cp2,
                                               const float* __restrict__ bg,
                                               const float* __restrict__ xb,
                                               float* __restrict__ rq,
                                               float* __restrict__ zb) {
  int base = (blockIdx.x * 256 + threadIdx.x) * 4;
  int row = base >> 10, col = base & (D_ - 1);
  float4 vr = {0.f, 0.f, 0.f, 0.f}, vz = {0.f, 0.f, 0.f, 0.f};
  #pragma unroll
  for (int s = 0; s < KS_; ++s) {
    size_t b = (size_t)s * (N_ * 2048) + (size_t)row * 2048 + col;
    float4 r = *(const float4*)&Cp2[b];
    float4 z = *(const float4*)&Cp2[b + 1024];
    vr.x += r.x; vr.y += r.y; vr.z += r.z; vr.w += r.w;
    vz.x += z.x; vz.y += z.y; vz.z += z.z; vz.w += z.w;
  }
  float4 x4 = *(const float4*)&xb[base];
  float4 g4 = *(const float4*)&bg[col];
  float4 ro, zo;
  ro.x = (1.f / (1.f + __expf(-vr.x))) * x4.x;
  ro.y = (1.f / (1.f + __expf(-vr.y))) * x4.y;
  ro.z = (1.f / (1.f + __expf(-vr.z))) * x4.z;
  ro.w = (1.f / (1.f + __expf(-vr.w))) * x4.w;
  zo.x = 1.f / (1.f + __expf(-(vz.x - g4.x)));
  zo.y = 1.f / (1.f + __expf(-(vz.y - g4.y)));
  zo.z = 1.f / (1.f + __expf(-(vz.z - g4.z)));
  zo.w = 1.f / (1.f + __expf(-(vz.w - g4.w)));
  *(float4*)&rq[base] = ro;
  *(float4*)&zb[base] = zo;
}

// ---------------------------------------------------------------- GRU1 h combine + LN2
__global__ __launch_bounds__(256) void comb_h_ln(const float* __restrict__ Cp,
                                                 const float* __restrict__ zbuf,
                                                 const float* __restrict__ xb,
                                                 const float* __restrict__ lg,
                                                 const float* __restrict__ lb,
                                                 float* __restrict__ h1,
                                                 float* __restrict__ hl) {
  int n = blockIdx.x, tid = threadIdx.x, c = tid * 4;
  float4 a4 = {0.f, 0.f, 0.f, 0.f};
  #pragma unroll
  for (int ss = 0; ss < KS_; ++ss) {
    float4 p = *(const float4*)&Cp[(size_t)ss * (N_ * D_) + (size_t)n * D_ + c];
    a4.x += p.x; a4.y += p.y; a4.z += p.z; a4.w += p.w;
  }
  float4 z4 = *(const float4*)&zbuf[(size_t)n * D_ + c];
  float4 x4 = *(const float4*)&xb[(size_t)n * D_ + c];
  float v[4];
  v[0] = (1.f - z4.x) * x4.x + z4.x * tanhf(a4.x);
  v[1] = (1.f - z4.y) * x4.y + z4.y * tanhf(a4.y);
  v[2] = (1.f - z4.z) * x4.z + z4.z * tanhf(a4.z);
  v[3] = (1.f - z4.w) * x4.w + z4.w * tanhf(a4.w);
  *(float4*)&h1[(size_t)n * D_ + c] = *(float4*)v;
  float s = v[0] + v[1] + v[2] + v[3];
  float q = v[0]*v[0] + v[1]*v[1] + v[2]*v[2] + v[3]*v[3];
  __shared__ float sa[4], sb[4];
  #pragma unroll
  for (int o = 32; o; o >>= 1) { s += __shfl_xor(s, o, 64); q += __shfl_xor(q, o, 64); }
  if ((tid & 63) == 0) { sa[tid >> 6] = s; sb[tid >> 6] = q; }
  __syncthreads();
  s = sa[0] + sa[1] + sa[2] + sa[3];
  q = sb[0] + sb[1] + sb[2] + sb[3];
  float mean = s * (1.f / D_);
  float var  = q * (1.f / D_) - mean * mean;
  float rstd = rsqrtf(var + 1e-5f);
  #pragma unroll
  for (int j = 0; j < 4; ++j)
    hl[(size_t)n * D_ + c + j] = (v[j] - mean) * rstd * lg[c + j] + lb[c + j];
}

// ---------------------------------------------------------------- GRU2 h combine -> hcur, out, optional LN1+qk(next)
__global__ __launch_bounds__(256) void comb_h2_lnqk(const float* __restrict__ Cp,
                                                    const float* __restrict__ zbuf,
                                                    const float* __restrict__ xb,
                                                    const float* __restrict__ lg,
                                                    const float* __restrict__ lb,
                                                    const float* __restrict__ Wq,
                                                    const float* __restrict__ Wk,
                                                    float* __restrict__ hcur,
                                                    float* __restrict__ outp,
                                                    int slot,
                                                    float* __restrict__ qkb) {
  int n = blockIdx.x, tid = threadIdx.x, c = tid * 4;
  __shared__ float qln[D_], Qp[D_];
  float4 a4 = {0.f, 0.f, 0.f, 0.f};
  #pragma unroll
  for (int ss = 0; ss < KS_; ++ss) {
    float4 p = *(const float4*)&Cp[(size_t)ss * (N_ * D_) + (size_t)n * D_ + c];
    a4.x += p.x; a4.y += p.y; a4.z += p.z; a4.w += p.w;
  }
  float4 z4 = *(const float4*)&zbuf[(size_t)n * D_ + c];
  float4 x4 = *(const float4*)&xb[(size_t)n * D_ + c];
  float v[4];
  v[0] = (1.f - z4.x) * x4.x + z4.x * tanhf(a4.x);
  v[1] = (1.f - z4.y) * x4.y + z4.y * tanhf(a4.y);
  v[2] = (1.f - z4.z) * x4.z + z4.z * tanhf(a4.z);
  v[3] = (1.f - z4.w) * x4.w + z4.w * tanhf(a4.w);
  *(float4*)&hcur[(size_t)n * D_ + c] = *(float4*)v;
  size_t bi = (slot >= 0) ? (((size_t)n * NB_ + slot) * D_ + c)
                          : ((size_t)n * D_ + c);
  *(float4*)&outp[bi] = *(float4*)v;
  if (Wq != nullptr)
    ln_qk_epilogue(n, v, tid, lg, lb, Wq, Wk, qkb, qln, Qp);
}

// ----------------------------------------------------------------
extern "C" void kernel_launch(void* const* d_in, const int* in_sizes, int n_in,
                              void* d_out, int out_size, void* d_ws, size_t ws_size,
                              hipStream_t stream) {
  const float* x    = (const float*)d_in[0];
  const float* mem  = (const float*)d_in[1];
  const int*   mask = (const int*)d_in[2];
  const int*   midx = (const int*)d_in[3];
  const float* We   = (const float*)d_in[5];
  const float* be   = (const float*)d_in[6];
  const float* Wq   = (const float*)d_in[7];
  const float* Wk   = (const float*)d_in[8];
  const float* Wv   = (const float*)d_in[9];
  const float* Wo   = (const float*)d_in[10];
  const float* bo   = (const float*)d_in[11];
  const float* Wfc  = (const float*)d_in[12];
  const float* bfc  = (const float*)d_in[13];
  const float* ln1g = (const float*)d_in[14];
  const float* ln1b = (const float*)d_in[15];
  const float* ln2g = (const float*)d_in[16];
  const float* ln2b = (const float*)d_in[17];
  const float* lnkg = (const float*)d_in[18];
  const float* lnkb = (const float*)d_in[19];
  const float* g1w[7]; for (int j = 0; j < 7; ++j) g1w[j] = (const float*)d_in[20 + j];
  const float* g2w[7]; for (int j = 0; j < 7; ++j) g2w[j] = (const float*)d_in[27 + j];
  float* out = (float*)d_out;
  float* out_li = out + (size_t)N_ * D_;

  float* ws   = (float*)d_ws;
  float* pos  = ws; ws += (size_t)T_ * D_;
  float* hcur = ws; ws += N_ * D_;
  float* qkb  = ws; ws += N_ * D_;
  float* tb   = ws; ws += N_ * D_;
  float* ao   = ws; ws += N_ * D_;
  float* rq   = ws; ws += N_ * D_;
  float* zb   = ws; ws += N_ * D_;
  float* h1   = ws; ws += N_ * D_;
  float* hl   = ws; ws += N_ * D_;
  float* fwd  = ws; ws += N_ * D_;
  float* gpart = ws; ws += (size_t)KS_ * N_ * 2048;   // 8 MB
  float* pav   = ws; ws += (size_t)N_ * NCV_ * D_;    // 16 MB
  float* pm    = ws; ws += (size_t)N_ * NCV_ * H_;
  float* ps    = ws; ws += (size_t)N_ * NCV_ * H_;

  const dim3 gp(32, KS_);            // 256 blocks, 256 threads
  const dim3 at_grid(NCV_ / 4, N_);  // 1024 blocks

  pos_kernel<<<T_, 512, 0, stream>>>(pos);

  gemm_part_t<32, 1024, false><<<gp, 256, 0, stream>>>(x, We, nullptr, nullptr, nullptr, nullptr, gpart);
  comb_embed_lnqk<<<N_, 256, 0, stream>>>(gpart, be, ln1g, ln1b, Wq, Wk, hcur, out_li, qkb);

  for (int i = 0; i < NB_; ++i) {
    size_t oD  = (size_t)i * D_;
    size_t oDD = (size_t)i * D_ * D_;
    size_t oH  = (size_t)i * H_ * DH_ * DH_;

    attn_stream<<<at_grid, 256, 0, stream>>>(mem, pos, mask, midx, qkb,
                                             lnkg + oD, lnkb + oD, i, pav, pm, ps);
    attn_fin<<<N_, 256, 0, stream>>>(pav, pm, ps, Wv + oH, tb);

    gemm_part_t<32, 1024, false><<<gp, 256, 0, stream>>>(tb, Wo + oDD, nullptr, nullptr, nullptr, nullptr, gpart);
    comb_ew<<<128, 256, 0, stream>>>(gpart, bo + oD, ao, 1);

    // GRU1: x=hcur, y=ao
    gemm_part_t<64, 2048, true><<<gp, 256, 0, stream>>>(ao, g1w[0] + oDD, g1w[2] + oDD,
                                                        hcur, g1w[1] + oDD, g1w[3] + oDD, gpart);
    comb_rz<<<128, 256, 0, stream>>>(gpart, g1w[6] + oD, hcur, rq, zb);
    gemm_part_t<32, 1024, true><<<gp, 256, 0, stream>>>(ao, g1w[4] + oDD, nullptr,
                                                        rq, g1w[5] + oDD, nullptr, gpart);
    comb_h_ln<<<N_, 256, 0, stream>>>(gpart, zb, hcur, ln2g + oD, ln2b + oD, h1, hl);

    gemm_part_t<32, 1024, false><<<gp, 256, 0, stream>>>(hl, Wfc + oDD, nullptr, nullptr, nullptr, nullptr, gpart);
    comb_ew<<<128, 256, 0, stream>>>(gpart, bfc + oD, fwd, 0);

    // GRU2: x=h1, y=fwd
    gemm_part_t<64, 2048, true><<<gp, 256, 0, stream>>>(fwd, g2w[0] + oDD, g2w[2] + oDD,
                                                        h1, g2w[1] + oDD, g2w[3] + oDD, gpart);
    comb_rz<<<128, 256, 0, stream>>>(gpart, g2w[6] + oD, h1, rq, zb);
    gemm_part_t<32, 1024, true><<<gp, 256, 0, stream>>>(fwd, g2w[4] + oDD, nullptr,
                                                        rq, g2w[5] + oDD, nullptr, gpart);

    bool last = (i == NB_ - 1);
    float* outp = last ? out : out_li;
    int slot = last ? -1 : (i + 1);
    const float* nWq = last ? nullptr : (Wq + oH + H_ * DH_ * DH_);
    const float* nWk = last ? nullptr : (Wk + oH + H_ * DH_ * DH_);
    const float* nlg = last ? nullptr : (ln1g + oD + D_);
    const float* nlb = last ? nullptr : (ln1b + oD + D_);
    comb_h2_lnqk<<<N_, 256, 0, stream>>>(gpart, zb, h1, nlg, nlb, nWq, nWk,
                                         hcur, outp, slot, qkb);
  }
}

// Round 15
// 802.258 us; speedup vs baseline: 1.9311x; 1.2310x over previous
//
#include <hip/hip_runtime.h>
#include <hip/hip_bf16.h>

#define N_   128
#define L_   512
#define NB_  4
#define D_   1024
#define H_   16
#define DH_  64
#define IN_  1024
#define T_   512

#define KS_  8       // GEMM K-splits (Kc = 128)
#define NCV_ 32      // attention chunks per sample (16 rows each)

typedef __attribute__((ext_vector_type(8))) short short8v;
typedef __attribute__((ext_vector_type(4))) float float4v;

__device__ __forceinline__ short f2bf(float f) {             // RNE f32->bf16
  unsigned u = __float_as_uint(f);
  u += 0x7FFFu + ((u >> 16) & 1u);
  return (short)(u >> 16);
}
__device__ __forceinline__ int pack2(float a, float b) {
  return (int)(unsigned short)f2bf(a) | ((int)f2bf(b) << 16);
}

// ---------------------------------------------------------------- pos table
__global__ __launch_bounds__(512) void pos_kernel(float* __restrict__ pos) {
  int t = blockIdx.x;
  int j = threadIdx.x;
  float seq = (float)(T_ - 1 - t);
  float ex  = (float)(2 * j) * (1.0f / (float)D_);
  float inv = expf(-ex * 9.210340371976184f);
  float si  = seq * inv;
  pos[(size_t)t * D_ + j]        = sinf(si);
  pos[(size_t)t * D_ + 512 + j]  = cosf(si);
}

// ---------------------------------------------------------------- MFMA split-K GEMM partials
// 256 threads = 4 waves; Kc=128; grid (32 col-tiles, 8 k-splits) = 256 blocks.
#define LDK_ 136   // padded k-row (shorts)
template<int COLW, int NC, bool HAS2>
__global__ __launch_bounds__(256) void gemm_part_t(const float* __restrict__ A1,
                                                   const float* __restrict__ B1a,
                                                   const float* __restrict__ B1b,
                                                   const float* __restrict__ A2,
                                                   const float* __restrict__ B2a,
                                                   const float* __restrict__ B2b,
                                                   float* __restrict__ Cpart) {
  constexpr int KC = 128;
  constexpr int CT = COLW / 16;
  __shared__ short As[N_ * LDK_];
  __shared__ short Bs[COLW * LDK_];
  const int tid = threadIdx.x;
  const int colg0 = blockIdx.x * COLW;
  const int k0 = blockIdx.y * KC;
  const float* B1 = B1a;
  const float* B2 = B2a;
  int col0 = colg0;
  if (NC == 2048 && colg0 >= 1024) { B1 = B1b; B2 = B2b; col0 = colg0 - 1024; }

  const int wid  = tid >> 6;
  const int lane = tid & 63;
  const int lrow = lane & 15;
  const int lk8  = (lane >> 4) * 8;
  const int wrow0 = wid * 32;

  float4v acc[2][CT];
  #pragma unroll
  for (int a = 0; a < 2; ++a)
    #pragma unroll
    for (int b = 0; b < CT; ++b)
      acc[a][b] = (float4v){0.f, 0.f, 0.f, 0.f};

  const int arow  = tid >> 1;             // A: 2 threads/row, 64 k each
  const int ahalf = (tid & 1) * 64;

  #pragma unroll
  for (int pass = 0; pass < (HAS2 ? 2 : 1); ++pass) {
    const float* A = pass ? A2 : A1;
    const float* B = pass ? B2 : B1;
    if (pass) __syncthreads();
    // ---- stage A[0:128, k0:k0+128] -> bf16
    {
      const float* ap = &A[(size_t)arow * D_ + k0 + ahalf];
      short* dst = &As[arow * LDK_ + ahalf];
      #pragma unroll
      for (int j = 0; j < 16; ++j) {
        float4 v = *(const float4*)&ap[4 * j];
        *(int2*)&dst[4 * j] = make_int2(pack2(v.x, v.y), pack2(v.z, v.w));
      }
    }
    // ---- stage B[k0:k0+128, col0:col0+COLW] -> bf16 Bs[col][k]
    if (COLW == 64) {
      const int bcol = tid & 63, bkq = (tid >> 6) * 32;
      int regs[16];
      #pragma unroll
      for (int j = 0; j < 16; ++j) {
        float v0 = B[(size_t)(k0 + bkq + 2 * j) * D_ + col0 + bcol];
        float v1 = B[(size_t)(k0 + bkq + 2 * j + 1) * D_ + col0 + bcol];
        regs[j] = pack2(v0, v1);
      }
      short* dst = &Bs[bcol * LDK_ + bkq];
      *(int4*)&dst[0]  = make_int4(regs[0],  regs[1],  regs[2],  regs[3]);
      *(int4*)&dst[8]  = make_int4(regs[4],  regs[5],  regs[6],  regs[7]);
      *(int4*)&dst[16] = make_int4(regs[8],  regs[9],  regs[10], regs[11]);
      *(int4*)&dst[24] = make_int4(regs[12], regs[13], regs[14], regs[15]);
    } else {
      const int bcol = tid & 31, bkq = (tid >> 5) * 16;
      int regs[8];
      #pragma unroll
      for (int j = 0; j < 8; ++j) {
        float v0 = B[(size_t)(k0 + bkq + 2 * j) * D_ + col0 + bcol];
        float v1 = B[(size_t)(k0 + bkq + 2 * j + 1) * D_ + col0 + bcol];
        regs[j] = pack2(v0, v1);
      }
      short* dst = &Bs[bcol * LDK_ + bkq];
      *(int4*)&dst[0] = make_int4(regs[0], regs[1], regs[2], regs[3]);
      *(int4*)&dst[8] = make_int4(regs[4], regs[5], regs[6], regs[7]);
    }
    __syncthreads();
    // ---- MFMA over 4 k-chunks of 32
    #pragma unroll
    for (int kk = 0; kk < KC; kk += 32) {
      short8v a0 = *(const short8v*)&As[(wrow0 + lrow)      * LDK_ + kk + lk8];
      short8v a1 = *(const short8v*)&As[(wrow0 + 16 + lrow) * LDK_ + kk + lk8];
      #pragma unroll
      for (int ct = 0; ct < CT; ++ct) {
        short8v bf = *(const short8v*)&Bs[(ct * 16 + lrow) * LDK_ + kk + lk8];
        acc[0][ct] = __builtin_amdgcn_mfma_f32_16x16x32_bf16(a0, bf, acc[0][ct], 0, 0, 0);
        acc[1][ct] = __builtin_amdgcn_mfma_f32_16x16x32_bf16(a1, bf, acc[1][ct], 0, 0, 0);
      }
    }
  }
  float* Cp = &Cpart[(size_t)blockIdx.y * (N_ * NC)];
  const int crow = (lane >> 4) * 4;
  const int ccol = lane & 15;
  #pragma unroll
  for (int rt = 0; rt < 2; ++rt)
    #pragma unroll
    for (int ct = 0; ct < CT; ++ct)
      #pragma unroll
      for (int j = 0; j < 4; ++j) {
        int row = wrow0 + rt * 16 + crow + j;
        int col = colg0 + ct * 16 + ccol;
        Cp[(size_t)row * NC + col] = acc[rt][ct][j];
      }
}

// ---------------------------------------------------------------- LN + qk fold (device helper)
__device__ __forceinline__ void ln_qk_epilogue(int n, const float* v4, int tid,
                                               const float* __restrict__ lg,
                                               const float* __restrict__ lb,
                                               const float* __restrict__ Wq,
                                               const float* __restrict__ Wk,
                                               float* __restrict__ qkb,
                                               float* qln, float* Qp) {
  int c = tid * 4;
  float s = v4[0] + v4[1] + v4[2] + v4[3];
  float q = v4[0]*v4[0] + v4[1]*v4[1] + v4[2]*v4[2] + v4[3]*v4[3];
  __shared__ float sa[4], sb[4];
  #pragma unroll
  for (int o = 32; o; o >>= 1) { s += __shfl_xor(s, o, 64); q += __shfl_xor(q, o, 64); }
  if ((tid & 63) == 0) { sa[tid >> 6] = s; sb[tid >> 6] = q; }
  __syncthreads();
  s = sa[0] + sa[1] + sa[2] + sa[3];
  q = sb[0] + sb[1] + sb[2] + sb[3];
  float mean = s * (1.f / D_);
  float var  = q * (1.f / D_) - mean * mean;
  float rstd = rsqrtf(var + 1e-5f);
  #pragma unroll
  for (int j = 0; j < 4; ++j)
    qln[c + j] = (v4[j] - mean) * rstd * lg[c + j] + lb[c + j];
  __syncthreads();
  #pragma unroll
  for (int j = 0; j < 4; ++j) {
    int idx = tid + j * 256; int h = idx >> 6, e = idx & 63;
    float acc = 0.f;
    for (int d = 0; d < DH_; ++d)
      acc += qln[(h << 6) + d] * Wq[((size_t)(h << 6) + d) * DH_ + e];
    Qp[idx] = acc;
  }
  __syncthreads();
  #pragma unroll
  for (int j = 0; j < 4; ++j) {
    int idx = tid + j * 256; int h = idx >> 6, d = idx & 63;
    float acc = 0.f;
    for (int e = 0; e < DH_; ++e)
      acc += Wk[((size_t)(h << 6) + d) * DH_ + e] * Qp[(h << 6) + e];
    qkb[(size_t)n * D_ + idx] = acc * 0.03125f;
  }
}

// ---------------------------------------------------------------- embed combine
__global__ __launch_bounds__(256) void comb_embed_lnqk(const float* __restrict__ Cp,
                                                       const float* __restrict__ bias,
                                                       const float* __restrict__ lg,
                                                       const float* __restrict__ lb,
                                                       const float* __restrict__ Wq,
                                                       const float* __restrict__ Wk,
                                                       float* __restrict__ hcur,
                                                       float* __restrict__ out_li,
                                                       float* __restrict__ qkb) {
  int n = blockIdx.x, tid = threadIdx.x, c = tid * 4;
  __shared__ float qln[D_], Qp[D_];
  float4 a4 = {0.f, 0.f, 0.f, 0.f};
  #pragma unroll
  for (int s = 0; s < KS_; ++s) {
    float4 p = *(const float4*)&Cp[(size_t)s * (N_ * D_) + (size_t)n * D_ + c];
    a4.x += p.x; a4.y += p.y; a4.z += p.z; a4.w += p.w;
  }
  float4 b4 = *(const float4*)&bias[c];
  float v[4] = {fmaxf(a4.x + b4.x, 0.f), fmaxf(a4.y + b4.y, 0.f),
                fmaxf(a4.z + b4.z, 0.f), fmaxf(a4.w + b4.w, 0.f)};
  *(float4*)&hcur[(size_t)n * D_ + c] = *(float4*)v;
  *(float4*)&out_li[((size_t)n * NB_ + 0) * D_ + c] = *(float4*)v;
  ln_qk_epilogue(n, v, tid, lg, lb, Wq, Wk, qkb, qln, Qp);
}

// ---------------------------------------------------------------- streaming attention
__global__ __launch_bounds__(256) void attn_stream(
    const float* __restrict__ mem, const float* __restrict__ pos,
    const int* __restrict__ mask, const int* __restrict__ midx,
    const float* __restrict__ qkv, const float* __restrict__ lng,
    const float* __restrict__ lnb, int blk,
    float* __restrict__ pav, float* __restrict__ pm, float* __restrict__ ps)
{
  const int n    = blockIdx.y;
  const int w    = threadIdx.x >> 6;
  const int lane = threadIdx.x & 63;
  const int vc   = blockIdx.x * 4 + w;
  const int l0   = vc * (L_ / NCV_);
  const int d0   = lane * 16;

  float g[16], bv[16], qv[16];
  #pragma unroll
  for (int j = 0; j < 4; ++j) {
    float4 t0 = *(const float4*)&lng[d0 + 4 * j];
    g[4*j+0] = t0.x; g[4*j+1] = t0.y; g[4*j+2] = t0.z; g[4*j+3] = t0.w;
    float4 t1 = *(const float4*)&lnb[d0 + 4 * j];
    bv[4*j+0] = t1.x; bv[4*j+1] = t1.y; bv[4*j+2] = t1.z; bv[4*j+3] = t1.w;
    float4 t2 = *(const float4*)&qkv[(size_t)n * D_ + d0 + 4 * j];
    qv[4*j+0] = t2.x; qv[4*j+1] = t2.y; qv[4*j+2] = t2.z; qv[4*j+3] = t2.w;
  }
  float m_run = -INFINITY, s_run = 0.f;
  float av[16];
  #pragma unroll
  for (int j = 0; j < 16; ++j) av[j] = 0.f;

  for (int l = l0; l < l0 + (L_ / NCV_); ++l) {
    if (mask[(size_t)n * L_ + l] == 0) continue;
    const float* xr = &mem[(((size_t)n * L_ + l) * NB_ + blk) * D_ + d0];
    const int tt = midx[(size_t)n * L_ + l];
    const float* pr = &pos[(size_t)tt * D_ + d0];
    float xv[16];
    #pragma unroll
    for (int j = 0; j < 4; ++j) {
      float4 a = *(const float4*)&xr[4 * j];
      float4 p = *(const float4*)&pr[4 * j];
      xv[4*j+0] = a.x + p.x; xv[4*j+1] = a.y + p.y;
      xv[4*j+2] = a.z + p.z; xv[4*j+3] = a.w + p.w;
    }
    float s1 = 0.f, s2 = 0.f;
    #pragma unroll
    for (int j = 0; j < 16; ++j) { s1 += xv[j]; s2 += xv[j] * xv[j]; }
    #pragma unroll
    for (int o = 32; o; o >>= 1) { s1 += __shfl_xor(s1, o, 64); s2 += __shfl_xor(s2, o, 64); }
    float mean = s1 * (1.f / D_);
    float var  = s2 * (1.f / D_) - mean * mean;
    float rstd = rsqrtf(var + 1e-5f);
    float e = 0.f;
    float y[16];
    #pragma unroll
    for (int j = 0; j < 16; ++j) {
      y[j] = (xv[j] - mean) * rstd * g[j] + bv[j];
      e += y[j] * qv[j];
    }
    e += __shfl_xor(e, 1, 64);
    e += __shfl_xor(e, 2, 64);
    float mn = fmaxf(m_run, e);
    float al = __expf(m_run - mn);
    float pw = __expf(e - mn);
    s_run = s_run * al + pw;
    #pragma unroll
    for (int j = 0; j < 16; ++j) av[j] = av[j] * al + pw * y[j];
    m_run = mn;
  }
  size_t base = ((size_t)n * NCV_ + vc) * D_ + d0;
  #pragma unroll
  for (int j = 0; j < 16; ++j) pav[base + j] = av[j];
  if ((lane & 3) == 0) {
    size_t mb = ((size_t)n * NCV_ + vc) * H_ + (lane >> 2);
    pm[mb] = m_run;
    ps[mb] = s_run;
  }
}

// ---------------------------------------------------------------- merge chunks + V-projection -> tb
__global__ __launch_bounds__(256) void attn_fin(const float* __restrict__ pav,
                                                const float* __restrict__ pm,
                                                const float* __restrict__ ps,
                                                const float* __restrict__ Wv,
                                                float* __restrict__ tb) {
  int n = blockIdx.x, tid = threadIdx.x;
  int d0 = tid * 4; int h = tid >> 4;
  float M = -INFINITY;
  for (int c = 0; c < NCV_; ++c) M = fmaxf(M, pm[((size_t)n * NCV_ + c) * H_ + h]);
  float S = 0.f, a0 = 0.f, a1 = 0.f, a2 = 0.f, a3 = 0.f;
  if (M > -INFINITY) {
    for (int c = 0; c < NCV_; ++c) {
      float mc = pm[((size_t)n * NCV_ + c) * H_ + h];
      if (mc == -INFINITY) continue;
      float wgt = __expf(mc - M);
      S += ps[((size_t)n * NCV_ + c) * H_ + h] * wgt;
      size_t ab = ((size_t)n * NCV_ + c) * D_ + d0;
      float4 v = *(const float4*)&pav[ab];
      a0 += v.x * wgt; a1 += v.y * wgt; a2 += v.z * wgt; a3 += v.w * wgt;
    }
  }
  float inv = (S > 0.f) ? 1.f / S : 0.f;
  __shared__ float att[D_];
  att[d0 + 0] = a0 * inv; att[d0 + 1] = a1 * inv;
  att[d0 + 2] = a2 * inv; att[d0 + 3] = a3 * inv;
  __syncthreads();
  #pragma unroll
  for (int j = 0; j < 4; ++j) {
    int idx = tid + j * 256; int hh = idx >> 6, e = idx & 63;
    float acc = 0.f;
    for (int d = 0; d < DH_; ++d)
      acc += att[(hh << 6) + d] * Wv[((size_t)(hh << 6) + d) * DH_ + e];
    tb[(size_t)n * D_ + idx] = acc;
  }
}

// ---------------------------------------------------------------- elementwise combine (float4)
__global__ __launch_bounds__(256) void comb_ew(const float* __restrict__ Cp,
                                               const float* __restrict__ bias,
                                               float* __restrict__ out, int mode) {
  int base = (blockIdx.x * 256 + threadIdx.x) * 4;
  int col = base & (D_ - 1);
  float4 a4 = {0.f, 0.f, 0.f, 0.f};
  #pragma unroll
  for (int s = 0; s < KS_; ++s) {
    float4 p = *(const float4*)&Cp[(size_t)s * (N_ * D_) + base];
    a4.x += p.x; a4.y += p.y; a4.z += p.z; a4.w += p.w;
  }
  float4 b4 = *(const float4*)&bias[col];
  a4.x += b4.x; a4.y += b4.y; a4.z += b4.z; a4.w += b4.w;
  if (mode == 0) {
    a4.x = fmaxf(a4.x, 0.f); a4.y = fmaxf(a4.y, 0.f);
    a4.z = fmaxf(a4.z, 0.f); a4.w = fmaxf(a4.w, 0.f);
  }
  *(float4*)&out[base] = a4;
}

// ---------------------------------------------------------------- GRU r,z combine (float4)
__global__ __launch_bounds__(256) void comb_rz(const float* __restrict__ Cp2,
                                               const float* __restrict__ bg,
                                               const float* __restrict__ xb,
                                               float* __restrict__ rq,
                                               float* __restrict__ zb) {
  int base = (blockIdx.x * 256 + threadIdx.x) * 4;
  int row = base >> 10, col = base & (D_ - 1);
  float4 vr = {0.f, 0.f, 0.f, 0.f}, vz = {0.f, 0.f, 0.f, 0.f};
  #pragma unroll
  for (int s = 0; s < KS_; ++s) {
    size_t b = (size_t)s * (N_ * 2048) + (size_t)row * 2048 + col;
    float4 r = *(const float4*)&Cp2[b];
    float4 z = *(const float4*)&Cp2[b + 1024];
    vr.x += r.x; vr.y += r.y; vr.z += r.z; vr.w += r.w;
    vz.x += z.x; vz.y += z.y; vz.z += z.z; vz.w += z.w;
  }
  float4 x4 = *(const float4*)&xb[base];
  float4 g4 = *(const float4*)&bg[col];
  float4 ro, zo;
  ro.x = (1.f / (1.f + __expf(-vr.x))) * x4.x;
  ro.y = (1.f / (1.f + __expf(-vr.y))) * x4.y;
  ro.z = (1.f / (1.f + __expf(-vr.z))) * x4.z;
  ro.w = (1.f / (1.f + __expf(-vr.w))) * x4.w;
  zo.x = 1.f / (1.f + __expf(-(vz.x - g4.x)));
  zo.y = 1.f / (1.f + __expf(-(vz.y - g4.y)));
  zo.z = 1.f / (1.f + __expf(-(vz.z - g4.z)));
  zo.w = 1.f / (1.f + __expf(-(vz.w - g4.w)));
  *(float4*)&rq[base] = ro;
  *(float4*)&zb[base] = zo;
}

// ---------------------------------------------------------------- GRU1 h combine + LN2
__global__ __launch_bounds__(256) void comb_h_ln(const float* __restrict__ Cp,
                                                 const float* __restrict__ zbuf,
                                                 const float* __restrict__ xb,
                                                 const float* __restrict__ lg,
                                                 const float* __restrict__ lb,
                                                 float* __restrict__ h1,
                                                 float* __restrict__ hl) {
  int n = blockIdx.x, tid = threadIdx.x, c = tid * 4;
  float4 a4 = {0.f, 0.f, 0.f, 0.f};
  #pragma unroll
  for (int ss = 0; ss < KS_; ++ss) {
    float4 p = *(const float4*)&Cp[(size_t)ss * (N_ * D_) + (size_t)n * D_ + c];
    a4.x += p.x; a4.y += p.y; a4.z += p.z; a4.w += p.w;
  }
  float4 z4 = *(const float4*)&zbuf[(size_t)n * D_ + c];
  float4 x4 = *(const float4*)&xb[(size_t)n * D_ + c];
  float v[4];
  v[0] = (1.f - z4.x) * x4.x + z4.x * tanhf(a4.x);
  v[1] = (1.f - z4.y) * x4.y + z4.y * tanhf(a4.y);
  v[2] = (1.f - z4.z) * x4.z + z4.z * tanhf(a4.z);
  v[3] = (1.f - z4.w) * x4.w + z4.w * tanhf(a4.w);
  *(float4*)&h1[(size_t)n * D_ + c] = *(float4*)v;
  float s = v[0] + v[1] + v[2] + v[3];
  float q = v[0]*v[0] + v[1]*v[1] + v[2]*v[2] + v[3]*v[3];
  __shared__ float sa[4], sb[4];
  #pragma unroll
  for (int o = 32; o; o >>= 1) { s += __shfl_xor(s, o, 64); q += __shfl_xor(q, o, 64); }
  if ((tid & 63) == 0) { sa[tid >> 6] = s; sb[tid >> 6] = q; }
  __syncthreads();
  s = sa[0] + sa[1] + sa[2] + sa[3];
  q = sb[0] + sb[1] + sb[2] + sb[3];
  float mean = s * (1.f / D_);
  float var  = q * (1.f / D_) - mean * mean;
  float rstd = rsqrtf(var + 1e-5f);
  #pragma unroll
  for (int j = 0; j < 4; ++j)
    hl[(size_t)n * D_ + c + j] = (v[j] - mean) * rstd * lg[c + j] + lb[c + j];
}

// ---------------------------------------------------------------- GRU2 h combine -> hcur, out, optional LN1+qk(next)
__global__ __launch_bounds__(256) void comb_h2_lnqk(const float* __restrict__ Cp,
                                                    const float* __restrict__ zbuf,
                                                    const float* __restrict__ xb,
                                                    const float* __restrict__ lg,
                                                    const float* __restrict__ lb,
                                                    const float* __restrict__ Wq,
                                                    const float* __restrict__ Wk,
                                                    float* __restrict__ hcur,
                                                    float* __restrict__ outp,
                                                    int slot,
                                                    float* __restrict__ qkb) {
  int n = blockIdx.x, tid = threadIdx.x, c = tid * 4;
  __shared__ float qln[D_], Qp[D_];
  float4 a4 = {0.f, 0.f, 0.f, 0.f};
  #pragma unroll
  for (int ss = 0; ss < KS_; ++ss) {
    float4 p = *(const float4*)&Cp[(size_t)ss * (N_ * D_) + (size_t)n * D_ + c];
    a4.x += p.x; a4.y += p.y; a4.z += p.z; a4.w += p.w;
  }
  float4 z4 = *(const float4*)&zbuf[(size_t)n * D_ + c];
  float4 x4 = *(const float4*)&xb[(size_t)n * D_ + c];
  float v[4];
  v[0] = (1.f - z4.x) * x4.x + z4.x * tanhf(a4.x);
  v[1] = (1.f - z4.y) * x4.y + z4.y * tanhf(a4.y);
  v[2] = (1.f - z4.z) * x4.z + z4.z * tanhf(a4.z);
  v[3] = (1.f - z4.w) * x4.w + z4.w * tanhf(a4.w);
  *(float4*)&hcur[(size_t)n * D_ + c] = *(float4*)v;
  size_t bi = (slot >= 0) ? (((size_t)n * NB_ + slot) * D_ + c)
                          : ((size_t)n * D_ + c);
  *(float4*)&outp[bi] = *(float4*)v;
  if (Wq != nullptr)
    ln_qk_epilogue(n, v, tid, lg, lb, Wq, Wk, qkb, qln, Qp);
}

// ----------------------------------------------------------------
extern "C" void kernel_launch(void* const* d_in, const int* in_sizes, int n_in,
                              void* d_out, int out_size, void* d_ws, size_t ws_size,
                              hipStream_t stream) {
  const float* x    = (const float*)d_in[0];
  const float* mem  = (const float*)d_in[1];
  const int*   mask = (const int*)d_in[2];
  const int*   midx = (const int*)d_in[3];
  const float* We   = (const float*)d_in[5];
  const float* be   = (const float*)d_in[6];
  const float* Wq   = (const float*)d_in[7];
  const float* Wk   = (const float*)d_in[8];
  const float* Wv   = (const float*)d_in[9];
  const float* Wo   = (const float*)d_in[10];
  const float* bo   = (const float*)d_in[11];
  const float* Wfc  = (const float*)d_in[12];
  const float* bfc  = (const float*)d_in[13];
  const float* ln1g = (const float*)d_in[14];
  const float* ln1b = (const float*)d_in[15];
  const float* ln2g = (const float*)d_in[16];
  const float* ln2b = (const float*)d_in[17];
  const float* lnkg = (const float*)d_in[18];
  const float* lnkb = (const float*)d_in[19];
  const float* g1w[7]; for (int j = 0; j < 7; ++j) g1w[j] = (const float*)d_in[20 + j];
  const float* g2w[7]; for (int j = 0; j < 7; ++j) g2w[j] = (const float*)d_in[27 + j];
  float* out = (float*)d_out;
  float* out_li = out + (size_t)N_ * D_;

  float* ws   = (float*)d_ws;
  float* pos  = ws; ws += (size_t)T_ * D_;
  float* hcur = ws; ws += N_ * D_;
  float* qkb  = ws; ws += N_ * D_;
  float* tb   = ws; ws += N_ * D_;
  float* ao   = ws; ws += N_ * D_;
  float* rq   = ws; ws += N_ * D_;
  float* zb   = ws; ws += N_ * D_;
  float* h1   = ws; ws += N_ * D_;
  float* hl   = ws; ws += N_ * D_;
  float* fwd  = ws; ws += N_ * D_;
  float* gpart = ws; ws += (size_t)KS_ * N_ * 2048;   // 8 MB
  float* pav   = ws; ws += (size_t)N_ * NCV_ * D_;    // 16 MB
  float* pm    = ws; ws += (size_t)N_ * NCV_ * H_;
  float* ps    = ws; ws += (size_t)N_ * NCV_ * H_;

  const dim3 gp(32, KS_);            // 256 blocks, 256 threads
  const dim3 at_grid(NCV_ / 4, N_);  // 1024 blocks

  pos_kernel<<<T_, 512, 0, stream>>>(pos);

  gemm_part_t<32, 1024, false><<<gp, 256, 0, stream>>>(x, We, nullptr, nullptr, nullptr, nullptr, gpart);
  comb_embed_lnqk<<<N_, 256, 0, stream>>>(gpart, be, ln1g, ln1b, Wq, Wk, hcur, out_li, qkb);

  for (int i = 0; i < NB_; ++i) {
    size_t oD  = (size_t)i * D_;
    size_t oDD = (size_t)i * D_ * D_;
    size_t oH  = (size_t)i * H_ * DH_ * DH_;

    attn_stream<<<at_grid, 256, 0, stream>>>(mem, pos, mask, midx, qkb,
                                             lnkg + oD, lnkb + oD, i, pav, pm, ps);
    attn_fin<<<N_, 256, 0, stream>>>(pav, pm, ps, Wv + oH, tb);

    gemm_part_t<32, 1024, false><<<gp, 256, 0, stream>>>(tb, Wo + oDD, nullptr, nullptr, nullptr, nullptr, gpart);
    comb_ew<<<128, 256, 0, stream>>>(gpart, bo + oD, ao, 1);

    // GRU1: x=hcur, y=ao
    gemm_part_t<64, 2048, true><<<gp, 256, 0, stream>>>(ao, g1w[0] + oDD, g1w[2] + oDD,
                                                        hcur, g1w[1] + oDD, g1w[3] + oDD, gpart);
    comb_rz<<<128, 256, 0, stream>>>(gpart, g1w[6] + oD, hcur, rq, zb);
    gemm_part_t<32, 1024, true><<<gp, 256, 0, stream>>>(ao, g1w[4] + oDD, nullptr,
                                                        rq, g1w[5] + oDD, nullptr, gpart);
    comb_h_ln<<<N_, 256, 0, stream>>>(gpart, zb, hcur, ln2g + oD, ln2b + oD, h1, hl);

    gemm_part_t<32, 1024, false><<<gp, 256, 0, stream>>>(hl, Wfc + oDD, nullptr, nullptr, nullptr, nullptr, gpart);
    comb_ew<<<128, 256, 0, stream>>>(gpart, bfc + oD, fwd, 0);

    // GRU2: x=h1, y=fwd
    gemm_part_t<64, 2048, true><<<gp, 256, 0, stream>>>(fwd, g2w[0] + oDD, g2w[2] + oDD,
                                                        h1, g2w[1] + oDD, g2w[3] + oDD, gpart);
    comb_rz<<<128, 256, 0, stream>>>(gpart, g2w[6] + oD, h1, rq, zb);
    gemm_part_t<32, 1024, true><<<gp, 256, 0, stream>>>(fwd, g2w[4] + oDD, nullptr,
                                                        rq, g2w[5] + oDD, nullptr, gpart);

    bool last = (i == NB_ - 1);
    float* outp = last ? out : out_li;
    int slot = last ? -1 : (i + 1);
    const float* nWq = last ? nullptr : (Wq + oH + H_ * DH_ * DH_);
    const float* nWk = last ? nullptr : (Wk + oH + H_ * DH_ * DH_);
    const float* nlg = last ? nullptr : (ln1g + oD + D_);
    const float* nlb = last ? nullptr : (ln1b + oD + D_);
    comb_h2_lnqk<<<N_, 256, 0, stream>>>(gpart, zb, h1, nlg, nlb, nWq, nWk,
                                         hcur, outp, slot, qkb);
  }
}